// Round 5
// baseline (254.393 us; speedup 1.0000x reference)
//
#include <hip/hip_runtime.h>

#define DIM   1024
#define LPR   32            // lanes cooperating on one row (2 rows per wave)
#define SEG   (DIM / LPR)   // 32 floats per lane
#define SEG4  (SEG / 4)     // 8 float4 per lane
#define ROWS_PER_BLOCK 8    // 256 threads / 32
#define WAVES_PER_BLOCK 4

typedef float f32x4 __attribute__((ext_vector_type(4)));

// ---------------- kernel 1: cos/sin table -> d_ws (permuted, SoA) ----------
// ws[loc]       = cos(angle[j]),  ws[DIM+loc] = sin(angle[j]),
// loc = (j&31)*32 + (j>>5)  so the main kernel's phase read cs[i*32+t] is
// linear in t (bank t, half-wave broadcast -> conflict-free).
__global__ void qll_table(const float* __restrict__ angles, float* __restrict__ ws) {
    int j = blockIdx.x * blockDim.x + threadIdx.x;
    if (j < DIM) {
        float a = angles[j];
        int loc = (j & 31) * LPR + (j >> 5);
        ws[loc]       = cosf(a);
        ws[DIM + loc] = sinf(a);
    }
}

// ---------------- main kernel ----------------------------------------------
// Row recurrence (Givens sweep): carry = value of column i entering step i.
//   out[i] = c_i*carry - s_i*v[i+1];  carry' = s_i*carry + c_i*v[i+1]
// Affine in carry -> per-lane (A,B) over 32 steps + 5-step shfl scan (width
// 32: the wave's two rows scan in parallel). All global traffic coalesced
// 1KB/instr; LDS staging uses the XOR-involution p(L)=L^((L>>3)&7) on BOTH
// the global source lane and the ds access index (rule 21).
__global__ __launch_bounds__(256, 4)
void qll_kernel(const float* __restrict__ x,
                const float* __restrict__ cs_ws,    // permuted SoA table or null
                const float* __restrict__ angles,   // fallback path only
                float* __restrict__ out,
                int batch)
{
    __shared__ f32x4 cstab4[DIM / 2];               // 8 KB: cos[1024] | sin[1024]
    __shared__ f32x4 stage[WAVES_PER_BLOCK][512];   // 32 KB, wave-private row pair
    float* cstab = (float*)cstab4;

    const int tid  = threadIdx.x;
    const int l    = tid & 63;        // lane in wave
    const int wave = tid >> 6;        // 0..3
    const int h    = (tid >> 5) & 1;  // which row of the wave's pair
    const int t    = tid & 31;        // segment index within row
    const int r0   = blockIdx.x * ROWS_PER_BLOCK + wave * 2;
    const bool active = (r0 + 2 <= batch);          // wave-uniform

    const int swz_l = l ^ ((l >> 3) & 7);           // involution on f32x4 index

    // ---- issue the row-pair staging FIRST (latency hides under table fill) ----
    const f32x4* gin = reinterpret_cast<const f32x4*>(x) + (size_t)r0 * 256;
    if (active) {
#pragma unroll
        for (int m = 0; m < 8; ++m) {
            __builtin_amdgcn_global_load_lds(
                (const __attribute__((address_space(1))) void*)(gin + m * 64 + swz_l),
                (__attribute__((address_space(3))) void*)(&stage[wave][m * 64]),
                16, 0, 0);
        }
    }

    // ---- cs table into LDS: linear copy from ws (zero conflicts, no trig) ----
    if (cs_ws) {
        const f32x4* w4 = reinterpret_cast<const f32x4*>(cs_ws);
        cstab4[tid]       = w4[tid];
        cstab4[256 + tid] = w4[256 + tid];
    } else {
        // fallback (ws too small): conflict-free order, compute trig in-block
        for (int f = tid; f < 2 * DIM; f += 256) {
            int loc = f & (DIM - 1);
            int j   = ((loc & 31) << 5) | (loc >> 5);   // inverse of loc(j)
            float a = angles[j];
            cstab[f] = (f < DIM) ? cosf(a) : sinf(a);
        }
    }
    __syncthreads();
    if (!active) return;
    asm volatile("s_waitcnt vmcnt(0)" ::: "memory");
    __builtin_amdgcn_sched_barrier(0);

    // ---- read this lane's 32-float segment (bank-balanced b128s) ----
    float v[SEG];
#pragma unroll
    for (int e = 0; e < SEG4; ++e) {
        f32x4 q = stage[wave][h * 256 + t * 8 + (e ^ (t & 7))];
        v[4*e+0] = q.x; v[4*e+1] = q.y; v[4*e+2] = q.z; v[4*e+3] = q.w;
    }

    // boundary exchanges (capture BEFORE phase 2 overwrites v[])
    float v0row = __shfl(v[0], 0, LPR);        // row's original column 0
    float v1row = __shfl(v[1], 0, LPR);
    float vnext = __shfl_down(v[0], 1, LPR);   // next lane's first elem (t=31 unused)

    // ---- phase 1: per-lane affine (A,B) with carry_in = 0 ----
    float A = 1.f, B = 0.f;
#pragma unroll
    for (int i = 0; i < SEG - 1; ++i) {
        float c = cstab[i * LPR + t];
        float s = cstab[DIM + i * LPR + t];
        B = s * B + c * v[i + 1];
        A = s * A;
    }
    {   // last step of segment consumes the boundary element
        float c = cstab[(SEG - 1) * LPR + t];
        float s = cstab[DIM + (SEG - 1) * LPR + t];
        B = s * B + c * vnext;   // lane 31: finite garbage, result unused
        A = s * A;
    }

    // ---- inclusive affine scan across 32 lanes (both rows in parallel) ----
#pragma unroll
    for (int d = 1; d < LPR; d <<= 1) {
        float pa = __shfl_up(A, d, LPR);
        float pb = __shfl_up(B, d, LPR);
        if (t >= d) { B = A * pb + B; A = A * pa; }
    }
    // exclusive prefix -> carry entering this lane's segment
    float ea = __shfl_up(A, 1, LPR);
    float eb = __shfl_up(B, 1, LPR);
    if (t == 0) { ea = 1.f; eb = 0.f; }
    float carry = ea * v0row + eb;

    // provisional out[0] (result of step 0), consumed by the wrap step 1023
    float c0 = cstab[0], s0 = cstab[DIM];      // loc(j=0) == 0; broadcast
    float out0_prov = c0 * v0row - s0 * v1row;

    // ---- phase 2: replay with true carry, outputs into v[] ----
#pragma unroll
    for (int i = 0; i < SEG - 1; ++i) {
        float c = cstab[i * LPR + t];
        float s = cstab[DIM + i * LPR + t];
        float vn = v[i + 1];
        float o  = c * carry - s * vn;
        carry    = s * carry + c * vn;
        v[i] = o;
    }
    {   // last step; lane 31 executes the wrap step 1023 against out[0]
        float c  = cstab[(SEG - 1) * LPR + t];
        float s  = cstab[DIM + (SEG - 1) * LPR + t];
        float vn = (t == LPR - 1) ? out0_prov : vnext;
        float o  = c * carry - s * vn;
        float nc = s * carry + c * vn;
        v[SEG - 1] = o;
        float out0_final = __shfl(nc, LPR - 1, LPR);  // lane 31 -> all
        if (t == 0) v[0] = out0_final;
    }

    // ---- out-stage into same buffer (same-wave DS pipe in-order), then
    //      coalesced nontemporal stores ----
#pragma unroll
    for (int e = 0; e < SEG4; ++e) {
        f32x4 q = { v[4*e+0], v[4*e+1], v[4*e+2], v[4*e+3] };
        stage[wave][h * 256 + t * 8 + (e ^ (t & 7))] = q;
    }
    f32x4* gout = reinterpret_cast<f32x4*>(out) + (size_t)r0 * 256;
#pragma unroll
    for (int m = 0; m < 8; ++m) {
        f32x4 q = stage[wave][m * 64 + swz_l];
        __builtin_nontemporal_store(q, gout + m * 64 + l);
    }
}

extern "C" void kernel_launch(void* const* d_in, const int* in_sizes, int n_in,
                              void* d_out, int out_size, void* d_ws, size_t ws_size,
                              hipStream_t stream) {
    const float* x      = (const float*)d_in[0];
    const float* angles = (const float*)d_in[1];
    float* outp         = (float*)d_out;

    int batch = in_sizes[0] / DIM;                              // 65536
    bool use_ws = (ws_size >= (size_t)(2 * DIM * sizeof(float)));
    const float* cs_ws = nullptr;
    if (use_ws) {
        qll_table<<<(DIM + 255) / 256, 256, 0, stream>>>(angles, (float*)d_ws);
        cs_ws = (const float*)d_ws;
    }
    int grid = (batch + ROWS_PER_BLOCK - 1) / ROWS_PER_BLOCK;   // 8192
    qll_kernel<<<grid, 256, 0, stream>>>(x, cs_ws, angles, outp, batch);
}

// Round 6
// 102.793 us; speedup vs baseline: 2.4748x; 2.4748x over previous
//
#include <hip/hip_runtime.h>

#define DIM   1024
#define LPR   32            // lanes cooperating on one row (2 rows per wave)
#define SEG   (DIM / LPR)   // 32 floats per lane
#define SEG4  (SEG / 4)     // 8 float4 per lane
#define ROWS_PER_BLOCK 8    // 256 threads / 32
#define WAVES_PER_BLOCK 4

typedef float f32x4 __attribute__((ext_vector_type(4)));

// Row recurrence (Givens sweep): carry = value of column i entering step i.
//   out[i]  = c_i*carry - s_i*v[i+1]
//   carry'  = s_i*carry + c_i*v[i+1]
// Affine in carry -> per-lane (A,B) + shfl scan parallelizes across 32 lanes
// (the wave's two rows scan in parallel in the same shfl instructions).
//
// All global traffic is coalesced 1KB/instr. Row-pair staged to LDS via
// global_load_lds: linear LDS dest + XOR involution p(L)=L^((L>>3)&7) applied
// to BOTH the global source lane offset and the ds access index (rule 21).
//
// vs r3 (90.7us): ONLY two changes —
//  (1) cs-table fill iterates over loc linearly (write bank = 2*loc%32, 2-way
//      = free) with j = rot5(loc) (self-inverse permutation); r3's fill had
//      all 32 lanes in bank 0 (the measured 8.9M conflict cycles).
//  (2) global_load_lds issued BEFORE the fill so HBM latency hides under it.
__global__ __launch_bounds__(256, 4)
void qll_kernel(const float* __restrict__ x,
                const float* __restrict__ angles,
                float* __restrict__ out,
                int batch)
{
    // cs transposed: step j at loc = (j&31)*32 + (j>>5) (10-bit rotate-by-5),
    // so the phase-loop read cs[i*32+t] is bank 2t%32, half-wave broadcast.
    __shared__ float2 cs[DIM];                      // 8 KB
    __shared__ f32x4  stage[WAVES_PER_BLOCK][512];  // 32 KB, wave-private row pair

    const int tid  = threadIdx.x;
    const int l    = tid & 63;        // lane in wave
    const int wave = tid >> 6;        // 0..3
    const int h    = (tid >> 5) & 1;  // which row of the wave's pair
    const int t    = tid & 31;        // segment index within row
    const int r0   = blockIdx.x * ROWS_PER_BLOCK + wave * 2;
    const bool active = (r0 + 2 <= batch);          // wave-uniform

    const int swz_l = l ^ ((l >> 3) & 7);           // involution on f32x4 index

    // ---- issue row-pair staging FIRST: latency hides under the table fill ----
    const f32x4* gin = reinterpret_cast<const f32x4*>(x) + (size_t)r0 * 256;
    if (active) {
#pragma unroll
        for (int m = 0; m < 8; ++m) {
            __builtin_amdgcn_global_load_lds(
                (const __attribute__((address_space(1))) void*)(gin + m * 64 + swz_l),
                (__attribute__((address_space(3))) void*)(&stage[wave][m * 64]),
                16, 0, 0);
        }
    }

    // ---- cs table fill, conflict-free write order (loc linear in lane) ----
    for (int loc = tid; loc < DIM; loc += 256) {
        int j = ((loc & 31) << 5) | (loc >> 5);     // rot5 = inverse of loc(j)
        float a = angles[j];
        cs[loc] = make_float2(cosf(a), sinf(a));
    }
    __syncthreads();
    if (!active) return;
    asm volatile("s_waitcnt vmcnt(0)" ::: "memory");
    __builtin_amdgcn_sched_barrier(0);

    // ---- read this lane's 32-float segment (bank-balanced b128s) ----
    float v[SEG];
#pragma unroll
    for (int e = 0; e < SEG4; ++e) {
        f32x4 q = stage[wave][h * 256 + t * 8 + (e ^ (t & 7))];
        v[4*e+0] = q.x; v[4*e+1] = q.y; v[4*e+2] = q.z; v[4*e+3] = q.w;
    }

    // boundary exchanges (capture BEFORE phase 2 overwrites v[])
    float v0row = __shfl(v[0], 0, LPR);        // row's original column 0
    float v1row = __shfl(v[1], 0, LPR);
    float vnext = __shfl_down(v[0], 1, LPR);   // next lane's first elem (t=31 unused)

    // ---- phase 1: per-lane affine (A,B) with carry_in = 0 ----
    float A = 1.f, B = 0.f;
#pragma unroll
    for (int i = 0; i < SEG - 1; ++i) {
        float2 w = cs[i * LPR + t];
        B = w.y * B + w.x * v[i + 1];
        A = w.y * A;
    }
    {   // last step of segment consumes the boundary element
        float2 w = cs[(SEG - 1) * LPR + t];
        B = w.y * B + w.x * vnext;   // lane 31: finite garbage, result unused
        A = w.y * A;
    }

    // ---- inclusive affine scan across 32 lanes (both rows in parallel) ----
#pragma unroll
    for (int d = 1; d < LPR; d <<= 1) {
        float pa = __shfl_up(A, d, LPR);
        float pb = __shfl_up(B, d, LPR);
        if (t >= d) { B = A * pb + B; A = A * pa; }
    }
    // exclusive prefix -> carry entering this lane's segment
    float ea = __shfl_up(A, 1, LPR);
    float eb = __shfl_up(B, 1, LPR);
    if (t == 0) { ea = 1.f; eb = 0.f; }
    float carry = ea * v0row + eb;

    // provisional out[0] (result of step 0), consumed by the wrap step 1023
    float2 w0 = cs[0];                 // loc(j=0) == 0; broadcast read
    float out0_prov = w0.x * v0row - w0.y * v1row;

    // ---- phase 2: replay with true carry, outputs into v[] ----
#pragma unroll
    for (int i = 0; i < SEG - 1; ++i) {
        float2 w = cs[i * LPR + t];
        float vn = v[i + 1];
        float o  = w.x * carry - w.y * vn;
        carry    = w.y * carry + w.x * vn;
        v[i] = o;
    }
    {   // last step; lane 31 executes the wrap step 1023 against out[0]
        float2 w  = cs[(SEG - 1) * LPR + t];
        float vn  = (t == LPR - 1) ? out0_prov : vnext;
        float o   = w.x * carry - w.y * vn;
        float nc  = w.y * carry + w.x * vn;
        v[SEG - 1] = o;
        float out0_final = __shfl(nc, LPR - 1, LPR);  // lane 31 -> all
        if (t == 0) v[0] = out0_final;
    }

    // ---- out-stage into same buffer (same-wave DS pipe in-order), then
    //      coalesced nontemporal stores ----
#pragma unroll
    for (int e = 0; e < SEG4; ++e) {
        f32x4 q = { v[4*e+0], v[4*e+1], v[4*e+2], v[4*e+3] };
        stage[wave][h * 256 + t * 8 + (e ^ (t & 7))] = q;
    }
    f32x4* gout = reinterpret_cast<f32x4*>(out) + (size_t)r0 * 256;
#pragma unroll
    for (int m = 0; m < 8; ++m) {
        f32x4 q = stage[wave][m * 64 + swz_l];
        __builtin_nontemporal_store(q, gout + m * 64 + l);
    }
}

extern "C" void kernel_launch(void* const* d_in, const int* in_sizes, int n_in,
                              void* d_out, int out_size, void* d_ws, size_t ws_size,
                              hipStream_t stream) {
    const float* x      = (const float*)d_in[0];
    const float* angles = (const float*)d_in[1];
    float* outp         = (float*)d_out;

    int batch = in_sizes[0] / DIM;                              // 65536
    int grid  = (batch + ROWS_PER_BLOCK - 1) / ROWS_PER_BLOCK;  // 8192
    qll_kernel<<<grid, 256, 0, stream>>>(x, angles, outp, batch);
}

// Round 7
// 90.838 us; speedup vs baseline: 2.8005x; 1.1316x over previous
//
#include <hip/hip_runtime.h>

#define DIM   1024
#define LPR   32            // lanes cooperating on one row (2 rows per wave)
#define SEG   (DIM / LPR)   // 32 floats per lane
#define SEG4  (SEG / 4)     // 8 float4 per lane
#define ROWS_PER_BLOCK 8    // 256 threads / 32
#define WAVES_PER_BLOCK 4

typedef float f32x4 __attribute__((ext_vector_type(4)));
#define AS1 __attribute__((address_space(1)))
#define AS3 __attribute__((address_space(3)))

// ---------------- kernel 1: permuted cos/sin table -> d_ws ------------------
// ws[loc] = (cos a_j, sin a_j), loc = (j&31)*32 + (j>>5)  (10-bit rot5), so
// the main kernel's phase read cs[i*32+t] is linear-in-t (2-way max = free).
__global__ void qll_table(const float* __restrict__ angles, float2* __restrict__ ws) {
    int j = blockIdx.x * blockDim.x + threadIdx.x;
    if (j < DIM) {
        float a = angles[j];
        ws[(j & 31) * LPR + (j >> 5)] = make_float2(cosf(a), sinf(a));
    }
}

// ---------------- main kernel ----------------------------------------------
// Row recurrence (Givens sweep): carry = value of column i entering step i.
//   out[i] = c_i*carry - s_i*v[i+1];  carry' = s_i*carry + c_i*v[i+1]
// Affine in carry -> per-lane (A,B) + width-32 shfl scan (the wave's two rows
// scan in parallel). All global traffic coalesced 1KB/instr; stage uses the
// XOR involution p(L)=L^((L>>3)&7) on BOTH global source lane and ds index.
//
// Prologue (vs r6): table comes from d_ws via 2 global_load_lds (L2-fast, no
// trig, no scattered reads). Counted vmcnt(8) waits ONLY for the table, then
// raw s_barrier (no compiler vmcnt(0) drain) keeps the 8 HBM row loads in
// flight; each wave drains its own with vmcnt(0) after the barrier.
__global__ __launch_bounds__(256, 4)
void qll_kernel(const float* __restrict__ x,
                const float2* __restrict__ csws,
                float* __restrict__ out,
                int batch)
{
    __shared__ float2 cs[DIM];                      // 8 KB
    __shared__ f32x4  stage[WAVES_PER_BLOCK][512];  // 32 KB, wave-private row pair

    const int tid  = threadIdx.x;
    const int l    = tid & 63;        // lane in wave
    const int wave = tid >> 6;        // 0..3
    const int h    = (tid >> 5) & 1;  // which row of the wave's pair
    const int t    = tid & 31;        // segment index within row
    const int r0   = blockIdx.x * ROWS_PER_BLOCK + wave * 2;
    const bool active = (r0 + 2 <= batch);          // wave-uniform
    const int rr   = active ? r0 : 0;               // clamp so all waves issue loads

    const int swz_l = l ^ ((l >> 3) & 7);           // involution on f32x4 index

    // ---- 1) table glds FIRST (oldest in vmcnt order; L2/L3-resident) ----
    const f32x4* w4 = reinterpret_cast<const f32x4*>(csws);
    f32x4* c4 = reinterpret_cast<f32x4*>(cs);
    __builtin_amdgcn_global_load_lds((const AS1 void*)(w4 + wave * 64 + l),
                                     (AS3 void*)(c4 + wave * 64), 16, 0, 0);
    __builtin_amdgcn_global_load_lds((const AS1 void*)(w4 + 256 + wave * 64 + l),
                                     (AS3 void*)(c4 + 256 + wave * 64), 16, 0, 0);

    // ---- 2) row-pair staging (HBM); stays in flight across the barrier ----
    const f32x4* gin = reinterpret_cast<const f32x4*>(x) + (size_t)rr * 256;
#pragma unroll
    for (int m = 0; m < 8; ++m) {
        __builtin_amdgcn_global_load_lds(
            (const AS1 void*)(gin + m * 64 + swz_l),
            (AS3 void*)(&stage[wave][m * 64]), 16, 0, 0);
    }

    // ---- 3) wait for the 2 oldest (table) only, then raw barrier ----
    asm volatile("s_waitcnt vmcnt(8)" ::: "memory");
    __builtin_amdgcn_s_barrier();
    if (!active) return;

    // ---- 4) own row data (wave-private -> own vmcnt suffices) ----
    asm volatile("s_waitcnt vmcnt(0)" ::: "memory");
    __builtin_amdgcn_sched_barrier(0);

    // ---- read this lane's 32-float segment (bank-balanced b128s) ----
    float v[SEG];
#pragma unroll
    for (int e = 0; e < SEG4; ++e) {
        f32x4 q = stage[wave][h * 256 + t * 8 + (e ^ (t & 7))];
        v[4*e+0] = q.x; v[4*e+1] = q.y; v[4*e+2] = q.z; v[4*e+3] = q.w;
    }

    // boundary exchanges (capture BEFORE phase 2 overwrites v[])
    float v0row = __shfl(v[0], 0, LPR);        // row's original column 0
    float v1row = __shfl(v[1], 0, LPR);
    float vnext = __shfl_down(v[0], 1, LPR);   // next lane's first elem (t=31 unused)

    // ---- phase 1: per-lane affine (A,B) with carry_in = 0 ----
    float A = 1.f, B = 0.f;
#pragma unroll
    for (int i = 0; i < SEG - 1; ++i) {
        float2 w = cs[i * LPR + t];
        B = w.y * B + w.x * v[i + 1];
        A = w.y * A;
    }
    {   // last step of segment consumes the boundary element
        float2 w = cs[(SEG - 1) * LPR + t];
        B = w.y * B + w.x * vnext;   // lane 31: finite garbage, result unused
        A = w.y * A;
    }

    // ---- inclusive affine scan across 32 lanes (both rows in parallel) ----
#pragma unroll
    for (int d = 1; d < LPR; d <<= 1) {
        float pa = __shfl_up(A, d, LPR);
        float pb = __shfl_up(B, d, LPR);
        if (t >= d) { B = A * pb + B; A = A * pa; }
    }
    // exclusive prefix -> carry entering this lane's segment
    float ea = __shfl_up(A, 1, LPR);
    float eb = __shfl_up(B, 1, LPR);
    if (t == 0) { ea = 1.f; eb = 0.f; }
    float carry = ea * v0row + eb;

    // provisional out[0] (result of step 0), consumed by the wrap step 1023
    float2 w0 = cs[0];                 // loc(j=0) == 0; broadcast read
    float out0_prov = w0.x * v0row - w0.y * v1row;

    // ---- phase 2: replay with true carry, outputs into v[] ----
#pragma unroll
    for (int i = 0; i < SEG - 1; ++i) {
        float2 w = cs[i * LPR + t];
        float vn = v[i + 1];
        float o  = w.x * carry - w.y * vn;
        carry    = w.y * carry + w.x * vn;
        v[i] = o;
    }
    {   // last step; lane 31 executes the wrap step 1023 against out[0]
        float2 w  = cs[(SEG - 1) * LPR + t];
        float vn  = (t == LPR - 1) ? out0_prov : vnext;
        float o   = w.x * carry - w.y * vn;
        float nc  = w.y * carry + w.x * vn;
        v[SEG - 1] = o;
        float out0_final = __shfl(nc, LPR - 1, LPR);  // lane 31 -> all
        if (t == 0) v[0] = out0_final;
    }

    // ---- out-stage into same buffer (same-wave DS pipe in-order), then
    //      coalesced nontemporal stores ----
#pragma unroll
    for (int e = 0; e < SEG4; ++e) {
        f32x4 q = { v[4*e+0], v[4*e+1], v[4*e+2], v[4*e+3] };
        stage[wave][h * 256 + t * 8 + (e ^ (t & 7))] = q;
    }
    f32x4* gout = reinterpret_cast<f32x4*>(out) + (size_t)r0 * 256;
#pragma unroll
    for (int m = 0; m < 8; ++m) {
        f32x4 q = stage[wave][m * 64 + swz_l];
        __builtin_nontemporal_store(q, gout + m * 64 + l);
    }
}

// ---------------- fallback (ws too small): r6's self-contained kernel ------
__global__ __launch_bounds__(256, 4)
void qll_kernel_fb(const float* __restrict__ x,
                   const float* __restrict__ angles,
                   float* __restrict__ out,
                   int batch)
{
    __shared__ float2 cs[DIM];
    __shared__ f32x4  stage[WAVES_PER_BLOCK][512];

    const int tid  = threadIdx.x;
    const int l    = tid & 63;
    const int wave = tid >> 6;
    const int h    = (tid >> 5) & 1;
    const int t    = tid & 31;
    const int r0   = blockIdx.x * ROWS_PER_BLOCK + wave * 2;
    const bool active = (r0 + 2 <= batch);
    const int swz_l = l ^ ((l >> 3) & 7);

    for (int loc = tid; loc < DIM; loc += 256) {
        int j = ((loc & 31) << 5) | (loc >> 5);
        float a = angles[j];
        cs[loc] = make_float2(cosf(a), sinf(a));
    }
    __syncthreads();
    if (!active) return;

    const f32x4* gin = reinterpret_cast<const f32x4*>(x) + (size_t)r0 * 256;
#pragma unroll
    for (int m = 0; m < 8; ++m) {
        __builtin_amdgcn_global_load_lds(
            (const AS1 void*)(gin + m * 64 + swz_l),
            (AS3 void*)(&stage[wave][m * 64]), 16, 0, 0);
    }
    asm volatile("s_waitcnt vmcnt(0)" ::: "memory");
    __builtin_amdgcn_sched_barrier(0);

    float v[SEG];
#pragma unroll
    for (int e = 0; e < SEG4; ++e) {
        f32x4 q = stage[wave][h * 256 + t * 8 + (e ^ (t & 7))];
        v[4*e+0] = q.x; v[4*e+1] = q.y; v[4*e+2] = q.z; v[4*e+3] = q.w;
    }
    float v0row = __shfl(v[0], 0, LPR);
    float v1row = __shfl(v[1], 0, LPR);
    float vnext = __shfl_down(v[0], 1, LPR);

    float A = 1.f, B = 0.f;
#pragma unroll
    for (int i = 0; i < SEG - 1; ++i) {
        float2 w = cs[i * LPR + t];
        B = w.y * B + w.x * v[i + 1];
        A = w.y * A;
    }
    {
        float2 w = cs[(SEG - 1) * LPR + t];
        B = w.y * B + w.x * vnext;
        A = w.y * A;
    }
#pragma unroll
    for (int d = 1; d < LPR; d <<= 1) {
        float pa = __shfl_up(A, d, LPR);
        float pb = __shfl_up(B, d, LPR);
        if (t >= d) { B = A * pb + B; A = A * pa; }
    }
    float ea = __shfl_up(A, 1, LPR);
    float eb = __shfl_up(B, 1, LPR);
    if (t == 0) { ea = 1.f; eb = 0.f; }
    float carry = ea * v0row + eb;

    float2 w0 = cs[0];
    float out0_prov = w0.x * v0row - w0.y * v1row;

#pragma unroll
    for (int i = 0; i < SEG - 1; ++i) {
        float2 w = cs[i * LPR + t];
        float vn = v[i + 1];
        float o  = w.x * carry - w.y * vn;
        carry    = w.y * carry + w.x * vn;
        v[i] = o;
    }
    {
        float2 w  = cs[(SEG - 1) * LPR + t];
        float vn  = (t == LPR - 1) ? out0_prov : vnext;
        float o   = w.x * carry - w.y * vn;
        float nc  = w.y * carry + w.x * vn;
        v[SEG - 1] = o;
        float out0_final = __shfl(nc, LPR - 1, LPR);
        if (t == 0) v[0] = out0_final;
    }
#pragma unroll
    for (int e = 0; e < SEG4; ++e) {
        f32x4 q = { v[4*e+0], v[4*e+1], v[4*e+2], v[4*e+3] };
        stage[wave][h * 256 + t * 8 + (e ^ (t & 7))] = q;
    }
    f32x4* gout = reinterpret_cast<f32x4*>(out) + (size_t)r0 * 256;
#pragma unroll
    for (int m = 0; m < 8; ++m) {
        f32x4 q = stage[wave][m * 64 + swz_l];
        __builtin_nontemporal_store(q, gout + m * 64 + l);
    }
}

extern "C" void kernel_launch(void* const* d_in, const int* in_sizes, int n_in,
                              void* d_out, int out_size, void* d_ws, size_t ws_size,
                              hipStream_t stream) {
    const float* x      = (const float*)d_in[0];
    const float* angles = (const float*)d_in[1];
    float* outp         = (float*)d_out;

    int batch = in_sizes[0] / DIM;                              // 65536
    int grid  = (batch + ROWS_PER_BLOCK - 1) / ROWS_PER_BLOCK;  // 8192

    if (ws_size >= (size_t)(DIM * sizeof(float2))) {
        float2* ws = (float2*)d_ws;
        qll_table<<<(DIM + 255) / 256, 256, 0, stream>>>(angles, ws);
        qll_kernel<<<grid, 256, 0, stream>>>(x, ws, outp, batch);
    } else {
        qll_kernel_fb<<<grid, 256, 0, stream>>>(x, angles, outp, batch);
    }
}